// Round 12
// baseline (3292.970 us; speedup 1.0000x reference)
//
#include <hip/hip_runtime.h>
#include <hip/hip_fp16.h>

// GRU 2-layer, B=256 S=1024 F=75 H=256.
// Round 12: R11 + (1) bank-conflict fixes: ctileT[8][4][65] (b32 writes, pad-65)
//  and hcat 16B-block XOR swizzle cb^=(row&7) on all reads/writes;
//  (2) safe L2-probe exchange: publish to BOTH a probe buffer (sc0 -> local L2)
//  and the definitive buffer (sc0 sc1 -> MALL). Readers issue both gathers
//  async; vmcnt(4) pins the probe 4; tag-EQUALITY selects probe if fresh, else
//  vmcnt(0) + definitive, else blocking retry. Separate probe buffer removes
//  any L2-eviction ordering hazard; both buffers memset per launch.
//  WAW on gather regs: one loop-top vmcnt(0) (drains only phase-old ops).

#define NS 1024
#define NF 75
#define NH 256

#define W0S 360   // halves: 96(x pad) + 256(h) + 8 pad
#define W1S 520   // 256(h0) + 256(h1) + 8 pad
#define HCS 520   // hcat row halves (64 used 16B-blocks + pad block)
#define XSS 104   // 96 + 8 pad

#define W0_HALVES (48 * W0S)                 // 17280
#define W1_HALVES (48 * W1S)                 // 24960
#define IMG_HALVES (W0_HALVES + W1_HALVES)   // 42240 halves = 84480 B

// shared aliasing offsets (bytes)
#define HCAT_OFF 0          // 16*520*2 = 16640
#define XS_OFF   16640      // 6656 -> 23296
#define CT_OFF   23296      // ctileT 8*4*65*4 = 8320 -> 31616
#define RED_OFF  31616      // 1088 -> 32704 (< 84480)

// d_ws layout (bytes)
#define WIMG_OFF 0
#define WIMG_BYTES (16 * IMG_HALVES * 2)     // 1,351,680
#define HXBUF_BYTES (2 * 16 * 16 * 256 * 4)  // 524,288 per buffer
#define HX0_OFF  WIMG_BYTES
#define HX1_OFF  (HX0_OFF + HXBUF_BYTES)
#define HXL0_OFF (HX1_OFF + HXBUF_BYTES)
#define HXL1_OFF (HXL0_OFF + HXBUF_BYTES)
#define HX_CLEAR_BYTES (4 * HXBUF_BYTES)     // 2 MiB

typedef _Float16 f16x8 __attribute__((ext_vector_type(8)));
typedef float f32x4 __attribute__((ext_vector_type(4)));
typedef unsigned int u32x4 __attribute__((ext_vector_type(4)));

#define PINV(x) asm volatile("" : "+v"(x))

__device__ __forceinline__ void bar_lds() {
  asm volatile("s_waitcnt lgkmcnt(0)" ::: "memory");
  __builtin_amdgcn_s_barrier();
  __builtin_amdgcn_sched_barrier(0);
}
__device__ __forceinline__ void drain_vm() {
  asm volatile("s_waitcnt vmcnt(0)" ::: "memory");
}

// stores: probe (sc0 -> local L2) and definitive (sc0 sc1 -> MALL)
__device__ __forceinline__ void st_u32_l2(unsigned* p, unsigned v) {
  asm volatile("global_store_dword %0, %1, off sc0" :: "v"(p), "v"(v) : "memory");
}
__device__ __forceinline__ void st_u32_sys(unsigned* p, unsigned v) {
  asm volatile("global_store_dword %0, %1, off sc0 sc1" :: "v"(p), "v"(v) : "memory");
}
// async issues (no waitcnt)
__device__ __forceinline__ void issue4_l2(const unsigned* p, u32x4& a, u32x4& b,
                                          u32x4& c, u32x4& d) {
  asm volatile(
      "global_load_dwordx4 %0, %4, off sc0\n\t"
      "global_load_dwordx4 %1, %4, off offset:16 sc0\n\t"
      "global_load_dwordx4 %2, %4, off offset:32 sc0\n\t"
      "global_load_dwordx4 %3, %4, off offset:48 sc0"
      : "=&v"(a), "=&v"(b), "=&v"(c), "=&v"(d) : "v"(p) : "memory");
}
__device__ __forceinline__ void issue4_sys(const unsigned* p, u32x4& a, u32x4& b,
                                           u32x4& c, u32x4& d) {
  asm volatile(
      "global_load_dwordx4 %0, %4, off sc0 sc1\n\t"
      "global_load_dwordx4 %1, %4, off offset:16 sc0 sc1\n\t"
      "global_load_dwordx4 %2, %4, off offset:32 sc0 sc1\n\t"
      "global_load_dwordx4 %3, %4, off offset:48 sc0 sc1"
      : "=&v"(a), "=&v"(b), "=&v"(c), "=&v"(d) : "v"(p) : "memory");
}
// blocking reload (retry path, definitive)
__device__ __forceinline__ void ld4b_sys(const unsigned* p, u32x4& a, u32x4& b,
                                         u32x4& c, u32x4& d) {
  asm volatile(
      "global_load_dwordx4 %0, %4, off sc0 sc1\n\t"
      "global_load_dwordx4 %1, %4, off offset:16 sc0 sc1\n\t"
      "global_load_dwordx4 %2, %4, off offset:32 sc0 sc1\n\t"
      "global_load_dwordx4 %3, %4, off offset:48 sc0 sc1\n\t"
      "s_waitcnt vmcnt(0)"
      : "=&v"(a), "=&v"(b), "=&v"(c), "=&v"(d) : "v"(p) : "memory");
}

__device__ __forceinline__ bool tags_ok(const u32x4& a, const u32x4& b,
                                        const u32x4& c, const u32x4& e, unsigned tg) {
  u32x4 m4 = __builtin_elementwise_min(__builtin_elementwise_min(a, b),
                                       __builtin_elementwise_min(c, e));
  unsigned m = m4.x;
  m = m4.y < m ? m4.y : m;
  m = m4.z < m ? m4.z : m;
  m = m4.w < m ? m4.w : m;
  return (m >> 16) == tg;   // equality: stale-run tags (>tg) also rejected
}

// hcat 16B-block swizzle: half-offset within a row for block cb (0..63)
__device__ __forceinline__ int swzb(int row, int cb) {
  return ((cb ^ (row & 7)) << 3);
}

__device__ __forceinline__ void unpack_swz(_Float16* rowbase, int row, int cb0,
                                           const u32x4& a, const u32x4& b,
                                           const u32x4& c, const u32x4& e) {
  u32x4 w0 = { (a.x & 0xffffu) | (a.y << 16), (a.z & 0xffffu) | (a.w << 16),
               (b.x & 0xffffu) | (b.y << 16), (b.z & 0xffffu) | (b.w << 16) };
  u32x4 w1 = { (c.x & 0xffffu) | (c.y << 16), (c.z & 0xffffu) | (c.w << 16),
               (e.x & 0xffffu) | (e.y << 16), (e.z & 0xffffu) | (e.w << 16) };
  *(u32x4*)(rowbase + swzb(row, cb0))     = w0;
  *(u32x4*)(rowbase + swzb(row, cb0 + 1)) = w1;
}

// Weight image per block j (halves): W0 [48][W0S] (x cols 0..74, h cols 96..351),
// W1 [48][W1S] (h0 cols 0..255, h1 cols 256..511); row = gate*16+u.
__global__ void prep_wimg(const float* __restrict__ wih0, const float* __restrict__ whh0,
                          const float* __restrict__ wih1, const float* __restrict__ whh1,
                          _Float16* __restrict__ wimg) {
  const int total = 16 * IMG_HALVES;
  for (int i = blockIdx.x * blockDim.x + threadIdx.x; i < total;
       i += gridDim.x * blockDim.x) {
    const int j = i / IMG_HALVES;
    int rem = i - j * IMG_HALVES;
    float val = 0.f;
    if (rem < W0_HALVES) {
      const int row = rem / W0S, k = rem - row * W0S;
      const int gate = row >> 4, u = row & 15;
      const int grow = gate * NH + j * 16 + u;
      if (k < NF) val = wih0[grow * NF + k];
      else if (k >= 96 && k < 352) val = whh0[grow * NH + (k - 96)];
    } else {
      rem -= W0_HALVES;
      const int row = rem / W1S, k = rem - row * W1S;
      const int gate = row >> 4, u = row & 15;
      const int grow = gate * NH + j * 16 + u;
      if (k < 256) val = wih1[grow * NH + k];
      else if (k < 512) val = whh1[grow * NH + (k - 256)];
    }
    wimg[i] = (_Float16)val;
  }
}

__global__ __launch_bounds__(512, 1) void gru_mfma(
    const float* __restrict__ x,
    const float* __restrict__ b_ih0, const float* __restrict__ b_hh0,
    const float* __restrict__ b_ih1, const float* __restrict__ b_hh1,
    const float* __restrict__ w_lin, const float* __restrict__ b_lin,
    const _Float16* __restrict__ wimg,
    unsigned* __restrict__ hx0, unsigned* __restrict__ hx1,
    unsigned* __restrict__ hxL0, unsigned* __restrict__ hxL1,
    float* __restrict__ out)
{
  const int tid = threadIdx.x;
  const int bid = blockIdx.x;
  const int gr = (bid & 7) + ((bid >> 7) << 3);
  const int j  = (bid >> 3) & 15;

  __shared__ f16x8 smem8[IMG_HALVES / 8];
  _Float16* Wst  = (_Float16*)smem8;
  _Float16* hcat = (_Float16*)((char*)smem8 + HCAT_OFF);
  _Float16* xs   = (_Float16*)((char*)smem8 + XS_OFF);
  float* ctileT  = (float*)((char*)smem8 + CT_OFF);      // [8][4][65]
  float (*red)[17] = (float(*)[17])((char*)smem8 + RED_OFF);

  int dead = 0, spins = 0;

  // ---- stage weight image ----
  {
    const float4* src = (const float4*)(wimg + (size_t)j * IMG_HALVES);
    float4* dst = (float4*)Wst;
    for (int i = tid; i < IMG_HALVES / 8; i += 512) dst[i] = src[i];
  }

  const int t8 = tid & 255;
  const int row = t8 >> 4, u = t8 & 15, gu = j * 16 + u;
  const int wid = tid >> 6, lane = tid & 63;
  const int lrow = lane & 15, lko = (lane >> 4) * 8;
  const int cbb = lane >> 4;                 // block sub-index for fragment reads
  const int chunk = gr * 4096 + row * 256 + u * 16;

  float gbr, gbz, gbnx, gbnh;
  if (tid < 256) {
    gbr  = b_ih0[gu] + b_hh0[gu];
    gbz  = b_ih0[NH + gu] + b_hh0[NH + gu];
    gbnx = b_ih0[2 * NH + gu];
    gbnh = b_hh0[2 * NH + gu];
  } else {
    gbr  = b_ih1[gu] + b_hh1[gu];
    gbz  = b_ih1[NH + gu] + b_hh1[NH + gu];
    gbnx = b_ih1[2 * NH + gu];
    gbnh = b_hh1[2 * NH + gu];
  }

  __syncthreads();   // Sa: weights staged

  // ---- hoist per-wave B-fragments (one tile per wave) ----
  _Float16* W0s = Wst;
  _Float16* W1s = Wst + W0_HALVES;
  f16x8 Bf[16];
  if (wid == 0) {            // ct0 = L0-r
    const _Float16* wb = W0s + lrow * W0S + lko;
    #pragma unroll
    for (int i = 0; i < 11; ++i) { Bf[i] = *(const f16x8*)(wb + i * 32); PINV(Bf[i]); }
  } else if (wid == 1) {     // ct1 = L0-z
    const _Float16* wb = W0s + (16 + lrow) * W0S + lko;
    #pragma unroll
    for (int i = 0; i < 11; ++i) { Bf[i] = *(const f16x8*)(wb + i * 32); PINV(Bf[i]); }
  } else if (wid == 2) {     // ct2 = L0-nx (x-part only)
    const _Float16* wb = W0s + (32 + lrow) * W0S + lko;
    #pragma unroll
    for (int i = 0; i < 3; ++i) { Bf[i] = *(const f16x8*)(wb + i * 32); PINV(Bf[i]); }
  } else if (wid == 3) {     // ct3 = L0-nh (h-part)
    const _Float16* wb = W0s + (32 + lrow) * W0S + lko;
    #pragma unroll
    for (int i = 0; i < 8; ++i) { Bf[i] = *(const f16x8*)(wb + (3 + i) * 32); PINV(Bf[i]); }
  } else if (wid == 4) {     // ct4 = L1-r (h0 then h1 cols)
    const _Float16* wn = W1s + lrow * W1S + lko;
    #pragma unroll
    for (int i = 0; i < 16; ++i) { Bf[i] = *(const f16x8*)(wn + i * 32); PINV(Bf[i]); }
  } else if (wid == 5) {     // ct5 = L1-z
    const _Float16* wn = W1s + (16 + lrow) * W1S + lko;
    #pragma unroll
    for (int i = 0; i < 16; ++i) { Bf[i] = *(const f16x8*)(wn + i * 32); PINV(Bf[i]); }
  } else if (wid == 6) {     // ct6 = L1-nx (h0 cols)
    const _Float16* wn = W1s + (32 + lrow) * W1S + lko;
    #pragma unroll
    for (int i = 0; i < 8; ++i) { Bf[i] = *(const f16x8*)(wn + i * 32); PINV(Bf[i]); }
  } else {                   // ct7 = L1-nh (h1 cols)
    const _Float16* wn = W1s + (32 + lrow) * W1S + lko;
    #pragma unroll
    for (int i = 0; i < 8; ++i) { Bf[i] = *(const f16x8*)(wn + (8 + i) * 32); PINV(Bf[i]); }
  }
  __syncthreads();   // Sb: hoist done, weight bytes may be clobbered

  for (int i = tid; i < 16 * HCS; i += 512) hcat[i] = (_Float16)0.f;
  for (int i = tid; i < 2 * 16 * XSS; i += 512) xs[i] = (_Float16)0.f;

  int xr_[3], xc_[3]; bool xv_[3];
  #pragma unroll
  for (int i = 0; i < 3; ++i) {
    const int idx = i * 512 + tid;
    xv_[i] = idx < 16 * NF;
    xr_[i] = xv_[i] ? idx / NF : 0;
    xc_[i] = xv_[i] ? idx % NF : 0;
  }
  const float* __restrict__ xbase = x + (size_t)(gr * 16) * NS * NF;
  #pragma unroll
  for (int i = 0; i < 3; ++i)
    if (xv_[i]) xs[xr_[i] * XSS + xc_[i]] =
        (_Float16)xbase[(size_t)xr_[i] * NS * NF + xc_[i]];

  float h0f = 0.f, h1f = 0.f;
  __syncthreads();   // Sc

  for (int p = 0; p <= NS; ++p) {
    const int par = p & 1;

    // loop-top WAW drain: everything outstanding is >= ~1 phase old -> ~free
    drain_vm();

    // (1) x prefetch
    float xf[3];
    if (p + 1 < NS) {
      #pragma unroll
      for (int i = 0; i < 3; ++i)
        if (xv_[i]) xf[i] = xbase[((size_t)xr_[i] * NS + (p + 1)) * NF + xc_[i]];
    }

    // (a) half1: async h1[p-2] gather — probe (L2) + definitive (MALL)
    u32x4 P0, P1, P2, P3, D0, D1, D2, D3;
    if (tid >= 256 && p >= 2) {
      issue4_l2 (hxL1 + par * 65536 + chunk, P0, P1, P2, P3);
      issue4_sys(hx1  + par * 65536 + chunk, D0, D1, D2, D3);
    }

    // (2)+(3) per-wave A-fragments + pre-barrier MFMAs
    const _Float16* __restrict__ xp = xs + par * (16 * XSS) + lrow * XSS + lko;
    const _Float16* __restrict__ hrow = hcat + lrow * HCS;
    f32x4 acc45 = {0.f, 0.f, 0.f, 0.f};   // wid4/5 carried across S2
    if (wid <= 1) {
      f16x8 xa0 = *(const f16x8*)(xp);
      f16x8 xa1 = *(const f16x8*)(xp + 32);
      f16x8 xa2 = *(const f16x8*)(xp + 64);
      f16x8 hfr[8];
      #pragma unroll
      for (int kb = 0; kb < 8; ++kb)
        hfr[kb] = *(const f16x8*)(hrow + swzb(lrow, 4 * kb + cbb));
      f32x4 a = {0.f, 0.f, 0.f, 0.f};
      a = __builtin_amdgcn_mfma_f32_16x16x32_f16(xa0, Bf[0], a, 0, 0, 0);
      a = __builtin_amdgcn_mfma_f32_16x16x32_f16(xa1, Bf[1], a, 0, 0, 0);
      a = __builtin_amdgcn_mfma_f32_16x16x32_f16(xa2, Bf[2], a, 0, 0, 0);
      #pragma unroll
      for (int kb = 0; kb < 8; ++kb)
        a = __builtin_amdgcn_mfma_f32_16x16x32_f16(hfr[kb], Bf[3 + kb], a, 0, 0, 0);
      ctileT[(wid * 4 + 0) * 65 + lane] = a.x;
      ctileT[(wid * 4 + 1) * 65 + lane] = a.y;
      ctileT[(wid * 4 + 2) * 65 + lane] = a.z;
      ctileT[(wid * 4 + 3) * 65 + lane] = a.w;
    } else if (wid == 2) {
      f16x8 xa0 = *(const f16x8*)(xp);
      f16x8 xa1 = *(const f16x8*)(xp + 32);
      f16x8 xa2 = *(const f16x8*)(xp + 64);
      f32x4 a = {0.f, 0.f, 0.f, 0.f};
      a = __builtin_amdgcn_mfma_f32_16x16x32_f16(xa0, Bf[0], a, 0, 0, 0);
      a = __builtin_amdgcn_mfma_f32_16x16x32_f16(xa1, Bf[1], a, 0, 0, 0);
      a = __builtin_amdgcn_mfma_f32_16x16x32_f16(xa2, Bf[2], a, 0, 0, 0);
      ctileT[(2 * 4 + 0) * 65 + lane] = a.x;
      ctileT[(2 * 4 + 1) * 65 + lane] = a.y;
      ctileT[(2 * 4 + 2) * 65 + lane] = a.z;
      ctileT[(2 * 4 + 3) * 65 + lane] = a.w;
    } else if (wid == 3) {
      f16x8 hfr[8];
      #pragma unroll
      for (int kb = 0; kb < 8; ++kb)
        hfr[kb] = *(const f16x8*)(hrow + swzb(lrow, 4 * kb + cbb));
      f32x4 a = {0.f, 0.f, 0.f, 0.f};
      #pragma unroll
      for (int kb = 0; kb < 8; ++kb)
        a = __builtin_amdgcn_mfma_f32_16x16x32_f16(hfr[kb], Bf[kb], a, 0, 0, 0);
      ctileT[(3 * 4 + 0) * 65 + lane] = a.x;
      ctileT[(3 * 4 + 1) * 65 + lane] = a.y;
      ctileT[(3 * 4 + 2) * 65 + lane] = a.z;
      ctileT[(3 * 4 + 3) * 65 + lane] = a.w;
    } else if (wid == 4 || wid == 5) {
      f16x8 hfr[8];
      #pragma unroll
      for (int kb = 0; kb < 8; ++kb)
        hfr[kb] = *(const f16x8*)(hrow + swzb(lrow, 4 * kb + cbb));
      #pragma unroll
      for (int kb = 0; kb < 8; ++kb)
        acc45 = __builtin_amdgcn_mfma_f32_16x16x32_f16(hfr[kb], Bf[kb], acc45, 0, 0, 0);
    } else if (wid == 6) {
      f16x8 hfr[8];
      #pragma unroll
      for (int kb = 0; kb < 8; ++kb)
        hfr[kb] = *(const f16x8*)(hrow + swzb(lrow, 4 * kb + cbb));
      f32x4 a = {0.f, 0.f, 0.f, 0.f};
      #pragma unroll
      for (int kb = 0; kb < 8; ++kb)
        a = __builtin_amdgcn_mfma_f32_16x16x32_f16(hfr[kb], Bf[kb], a, 0, 0, 0);
      ctileT[(6 * 4 + 0) * 65 + lane] = a.x;
      ctileT[(6 * 4 + 1) * 65 + lane] = a.y;
      ctileT[(6 * 4 + 2) * 65 + lane] = a.z;
      ctileT[(6 * 4 + 3) * 65 + lane] = a.w;
    }
    // wid7: no pre-barrier MFMA

    // (3.5) stage x[p+1]
    if (p + 1 < NS) {
      #pragma unroll
      for (int i = 0; i < 3; ++i)
        if (xv_[i]) xs[((p + 1) & 1) * (16 * XSS) + xr_[i] * XSS + xc_[i]] =
            (_Float16)xf[i];
    }
    bar_lds();   // S1: ct0..3,ct6 ready; hcat/xs(par) reads done

    // (4) CONCURRENT: half0 = L0 gates + double-publish h0[p];
    //                 half1 = validate h1[p-2] (probe-first)
    const int li = ((row >> 2) << 4) | u, rg = row & 3;
    if (tid < 256) {
      if (p < NS) {
        const float ar = ctileT[(0 * 4 + rg) * 65 + li] + gbr;
        const float az = ctileT[(1 * 4 + rg) * 65 + li] + gbz;
        const float nx = ctileT[(2 * 4 + rg) * 65 + li] + gbnx;
        const float nh = ctileT[(3 * 4 + rg) * 65 + li] + gbnh;
        const float r = 1.f / (1.f + __expf(-ar));
        const float z = 1.f / (1.f + __expf(-az));
        const float n = tanhf(nx + r * nh);
        h0f = (1.f - z) * n + z * h0f;
        union { _Float16 h; unsigned short s; } c; c.h = (_Float16)h0f;
        const unsigned v = (unsigned)c.s | ((unsigned)(p + 1) << 16);
        const int po = par * 65536 + gr * 4096 + row * 256 + gu;
        st_u32_l2 (hxL0 + po, v);
        st_u32_sys(hx0  + po, v);
      }
    } else {
      if (p >= 2) {
        const unsigned tg2 = (unsigned)(p - 1);
        asm volatile("s_waitcnt vmcnt(4)"
                     : "+v"(P0), "+v"(P1), "+v"(P2), "+v"(P3) :: "memory");
        if (!tags_ok(P0, P1, P2, P3, tg2)) {
          asm volatile("s_waitcnt vmcnt(0)"
                       : "+v"(D0), "+v"(D1), "+v"(D2), "+v"(D3) :: "memory");
          while (!tags_ok(D0, D1, D2, D3, tg2)) {
            if (++spins > 200000) { dead = 1; break; }
            __builtin_amdgcn_s_sleep(1);
            ld4b_sys(hx1 + par * 65536 + chunk, D0, D1, D2, D3);
          }
          P0 = D0; P1 = D1; P2 = D2; P3 = D3;
        }
        unpack_swz(hcat + row * HCS, row, 32 + 2 * u, P0, P1, P2, P3);
      }
    }
    bar_lds();   // S2: h1[p-2] in hcat; h0[p] published

    // (6) half0: async h0[p] gather (probe+definitive); waves 4/5/7: h1 MFMAs
    u32x4 A0, A1, A2, A3, E0, E1, E2, E3;
    if (tid < 256 && p < NS) {
      issue4_l2 (hxL0 + par * 65536 + chunk, A0, A1, A2, A3);
      issue4_sys(hx0  + par * 65536 + chunk, E0, E1, E2, E3);
    }
    if (wid == 4 || wid == 5) {
      f16x8 h1r[8];
      #pragma unroll
      for (int kb = 0; kb < 8; ++kb)
        h1r[kb] = *(const f16x8*)(hrow + swzb(lrow, 32 + 4 * kb + cbb));
      #pragma unroll
      for (int kb = 0; kb < 8; ++kb)
        acc45 = __builtin_amdgcn_mfma_f32_16x16x32_f16(h1r[kb], Bf[8 + kb], acc45, 0, 0, 0);
      ctileT[(wid * 4 + 0) * 65 + lane] = acc45.x;
      ctileT[(wid * 4 + 1) * 65 + lane] = acc45.y;
      ctileT[(wid * 4 + 2) * 65 + lane] = acc45.z;
      ctileT[(wid * 4 + 3) * 65 + lane] = acc45.w;
    } else if (wid == 7) {
      f16x8 h1r[8];
      #pragma unroll
      for (int kb = 0; kb < 8; ++kb)
        h1r[kb] = *(const f16x8*)(hrow + swzb(lrow, 32 + 4 * kb + cbb));
      f32x4 a = {0.f, 0.f, 0.f, 0.f};
      #pragma unroll
      for (int kb = 0; kb < 8; ++kb)
        a = __builtin_amdgcn_mfma_f32_16x16x32_f16(h1r[kb], Bf[kb], a, 0, 0, 0);
      ctileT[(7 * 4 + 0) * 65 + lane] = a.x;
      ctileT[(7 * 4 + 1) * 65 + lane] = a.y;
      ctileT[(7 * 4 + 2) * 65 + lane] = a.z;
      ctileT[(7 * 4 + 3) * 65 + lane] = a.w;
    }
    bar_lds();   // S3: ct4..7 ready

    // (7)/(8) CONCURRENT: half1 = L1 gates + double-publish h1[p-1];
    //                     half0 = validate h0[p] (probe-first)
    if (tid >= 256) {
      if (p >= 1) {
        const float ar = ctileT[(4 * 4 + rg) * 65 + li] + gbr;
        const float az = ctileT[(5 * 4 + rg) * 65 + li] + gbz;
        const float nx = ctileT[(6 * 4 + rg) * 65 + li] + gbnx;
        const float nh = ctileT[(7 * 4 + rg) * 65 + li] + gbnh;
        const float r = 1.f / (1.f + __expf(-ar));
        const float z = 1.f / (1.f + __expf(-az));
        const float n = tanhf(nx + r * nh);
        h1f = (1.f - z) * n + z * h1f;
        union { _Float16 h; unsigned short s; } c; c.h = (_Float16)h1f;
        const unsigned v = (unsigned)c.s | ((unsigned)p << 16);
        const int po = ((p - 1) & 1) * 65536 + gr * 4096 + row * 256 + gu;
        st_u32_l2 (hxL1 + po, v);
        st_u32_sys(hx1  + po, v);
      }
    } else {
      if (p < NS) {
        const unsigned tg0 = (unsigned)(p + 1);
        asm volatile("s_waitcnt vmcnt(4)"
                     : "+v"(A0), "+v"(A1), "+v"(A2), "+v"(A3) :: "memory");
        if (!tags_ok(A0, A1, A2, A3, tg0)) {
          asm volatile("s_waitcnt vmcnt(0)"
                       : "+v"(E0), "+v"(E1), "+v"(E2), "+v"(E3) :: "memory");
          while (!tags_ok(E0, E1, E2, E3, tg0)) {
            if (++spins > 200000) { dead = 1; break; }
            __builtin_amdgcn_s_sleep(1);
            ld4b_sys(hx0 + par * 65536 + chunk, E0, E1, E2, E3);
          }
          A0 = E0; A1 = E1; A2 = E2; A3 = E3;
        }
        unpack_swz(hcat + row * HCS, row, 2 * u, A0, A1, A2, A3);
      }
    }
    bar_lds();   // S4
  }

  // ---- final: half1 gathers h1[NS-1] (slot (NS-1)&1, tag NS, definitive) ----
  if (tid >= 256) {
    u32x4 C0, C1, C2, C3;
    const unsigned* src = hx1 + ((NS - 1) & 1) * 65536 + chunk;
    for (;;) {
      ld4b_sys(src, C0, C1, C2, C3);
      if (tags_ok(C0, C1, C2, C3, (unsigned)NS)) break;
      if (++spins > 200000) { dead = 1; break; }
      __builtin_amdgcn_s_sleep(1);
    }
    unpack_swz(hcat + row * HCS, row, 32 + 2 * u, C0, C1, C2, C3);
  }
  __syncthreads();
  if (tid < 256) {
    float part = 0.f;
    #pragma unroll
    for (int e = 0; e < 16; ++e) {
      const int ch = u * 16 + e;
      part += (float)hcat[row * HCS + swzb(row, 32 + (ch >> 3)) + (ch & 7)]
              * w_lin[ch];
    }
    red[row][u] = part;
  }
  __syncthreads();
  if (j == 0 && tid < 16) {
    float s = 0.f;
    #pragma unroll
    for (int e = 0; e < 16; ++e) s += red[tid][e];
    out[gr * 16 + tid] = s + b_lin[0];
  }
}

extern "C" void kernel_launch(void* const* d_in, const int* in_sizes, int n_in,
                              void* d_out, int out_size, void* d_ws, size_t ws_size,
                              hipStream_t stream) {
  (void)in_sizes; (void)n_in; (void)out_size; (void)ws_size;
  const float* x     = (const float*)d_in[0];
  const float* w_ih0 = (const float*)d_in[1];
  const float* w_hh0 = (const float*)d_in[2];
  const float* b_ih0 = (const float*)d_in[3];
  const float* b_hh0 = (const float*)d_in[4];
  const float* w_ih1 = (const float*)d_in[5];
  const float* w_hh1 = (const float*)d_in[6];
  const float* b_ih1 = (const float*)d_in[7];
  const float* b_hh1 = (const float*)d_in[8];
  const float* w_lin = (const float*)d_in[9];
  const float* b_lin = (const float*)d_in[10];

  char* ws = (char*)d_ws;
  _Float16* wimg = (_Float16*)(ws + WIMG_OFF);
  unsigned* hx0  = (unsigned*)(ws + HX0_OFF);
  unsigned* hx1  = (unsigned*)(ws + HX1_OFF);
  unsigned* hxL0 = (unsigned*)(ws + HXL0_OFF);
  unsigned* hxL1 = (unsigned*)(ws + HXL1_OFF);

  // Clear ALL tag space (definitive + probe) every launch: equality-check
  // safety requires no leftover tags from a previous replay.
  hipMemsetAsync(ws + HX0_OFF, 0, HX_CLEAR_BYTES, stream);
  prep_wimg<<<1024, 256, 0, stream>>>(w_ih0, w_hh0, w_ih1, w_hh1, wimg);
  gru_mfma<<<256, 512, 0, stream>>>(x, b_ih0, b_hh0, b_ih1, b_hh1,
                                    w_lin, b_lin, wimg, hx0, hx1, hxL0, hxL1,
                                    (float*)d_out);
}